// Round 13
// baseline (441.687 us; speedup 1.0000x reference)
//
#include <hip/hip_runtime.h>
#include <math.h>

#define N_NODES 100000
#define N_EDGES 1000000
#define NGRAPH 256
#define NP1 (N_NODES + 1)

#define NBUCK 196          // ceil(100000 / 512)
#define BUCKN 512
#define BUCKCAP 8192       // max raw edges/bucket (mean ~5120, ~40 sigma margin)
#define EPB 4096           // edges per S1 block
#define NBIN_BLOCKS ((N_EDGES + EPB - 1) / EPB)          // 245
#define NBOUND_BLOCKS ((N_NODES + 255) / 256)            // 391
#define WINCAP 10240       // fixed csr window per bucket
#define DUMMY ((unsigned)N_NODES)   // pad/tail col -> node with hs == 0

#define NGRP16 (N_NODES / 16)                 // 6250 node-groups of 16
#define HOP_BLOCKS ((((NGRP16 + 3) / 4)) * 4) // chunked hop grid

typedef unsigned short ushort_t;
typedef __attribute__((ext_vector_type(2))) float floatx2;
typedef __attribute__((ext_vector_type(2))) unsigned uintx2;

__device__ __forceinline__ ushort_t f2bf(float f) {   // round-to-nearest-even
    unsigned u = __float_as_uint(f);
    u += 0x7fffu + ((u >> 16) & 1u);
    return (ushort_t)(u >> 16);
}
__device__ __forceinline__ float bf2f(ushort_t u) {
    return __uint_as_float(((unsigned)u) << 16);
}
__device__ __forceinline__ float bf_lo(unsigned u) {
    return __uint_as_float(u << 16);
}
__device__ __forceinline__ float bf_hi(unsigned u) {
    return __uint_as_float(u & 0xffff0000u);
}
__device__ __forceinline__ unsigned pack2(float hi, float lo) {
    return ((unsigned)f2bf(hi) << 16) | (unsigned)f2bf(lo);
}
// fp8 e4m3 (OCP) HW converts, gfx950. Decode uint = 4 fp8 as two float pairs.
__device__ __forceinline__ floatx2 fp8_lo2(unsigned u) {
    return __builtin_amdgcn_cvt_pk_f32_fp8(u, false);   // bytes 0,1
}
__device__ __forceinline__ floatx2 fp8_hi2(unsigned u) {
    return __builtin_amdgcn_cvt_pk_f32_fp8(u, true);    // bytes 2,3
}
__device__ __forceinline__ unsigned f32_fp8x4(float a, float b, float c, float d) {
    unsigned w = __builtin_amdgcn_cvt_pk_fp8_f32(a, b, 0u, false);
    return __builtin_amdgcn_cvt_pk_fp8_f32(c, d, w, true);
}
__device__ __forceinline__ unsigned char f32_fp8(float a) {
    return (unsigned char)(__builtin_amdgcn_cvt_pk_fp8_f32(a, 0.f, 0u, false) & 0xffu);
}

using frag_ab = __attribute__((ext_vector_type(8))) short;
using frag_cd = __attribute__((ext_vector_type(4))) float;

// ------ S1 fused: blocks [0,NBIN_BLOCKS) bin edges; rest do graph bounds ----
__global__ __launch_bounds__(256) void k_binstage_bounds(const int* __restrict__ row,
        const int* __restrict__ col, int* __restrict__ gcursor,
        unsigned* __restrict__ slab,
        const int* __restrict__ batch, int* __restrict__ gbound) {
    __shared__ int lcount[NBUCK];
    __shared__ int lbase[NBUCK];
    int t = threadIdx.x;
    if (blockIdx.x >= NBIN_BLOCKS) {
        int n = (blockIdx.x - NBIN_BLOCKS) * 256 + t;
        if (n >= N_NODES) return;
        int b = batch[n];
        int prev = (n == 0) ? -1 : batch[n - 1];
        for (int g = prev + 1; g <= b; ++g) gbound[g] = n;
        if (n == N_NODES - 1) {
            for (int g = b + 1; g <= NGRAPH; ++g) gbound[g] = N_NODES;
        }
        return;
    }
    for (int i = t; i < NBUCK; i += 256) lcount[i] = 0;
    __syncthreads();
    int base = blockIdx.x * EPB;
    unsigned rec[16]; int bp[16];
#pragma unroll
    for (int k = 0; k < 16; ++k) {
        int e = base + k * 256 + t;
        if (e < N_EDGES) {
            int r = row[e], c = col[e];
            int b = r >> 9;
            int pos = atomicAdd(&lcount[b], 1);
            rec[k] = ((unsigned)(r & 511) << 17) | (unsigned)c;
            bp[k] = (b << 16) | pos;
        } else bp[k] = -1;
    }
    __syncthreads();
    for (int b = t; b < NBUCK; b += 256) {
        int c = lcount[b];
        lbase[b] = (c > 0) ? atomicAdd(&gcursor[b], c) : 0;
    }
    __syncthreads();
#pragma unroll
    for (int k = 0; k < 16; ++k) {
        if (bp[k] >= 0) {
            int b = bp[k] >> 16, pos = bp[k] & 0xffff;
            slab[(size_t)b * BUCKCAP + lbase[b] + pos] = rec[k];
        }
    }
}

// ------ S2: per-bucket CSR build into FIXED window b*WINCAP, pad-to-4 -------
__global__ __launch_bounds__(256) void k_bucket_build(const unsigned* __restrict__ slab,
        const int* __restrict__ gcursor,
        int* __restrict__ start, int* __restrict__ counts, float* __restrict__ dinv,
        unsigned* __restrict__ csr4) {
    __shared__ int ncount[BUCKN];
    __shared__ int nstart[BUCKN];
    __shared__ int sc[256];
    int b = blockIdx.x, t = threadIdx.x;
    int cnt = gcursor[b];
    int ebase = b * WINCAP;
    int node0 = b * BUCKN;
    int nn = min(BUCKN, N_NODES - node0);
    for (int i = t; i < nn; i += 256) ncount[i] = 0;
    __syncthreads();
    const unsigned* sl = slab + (size_t)b * BUCKCAP;
    for (int i = t; i < cnt; i += 256)
        atomicAdd(&ncount[sl[i] >> 17], 1);
    __syncthreads();
    int c0 = (2 * t < nn) ? ncount[2 * t] : 0;
    int c1 = (2 * t + 1 < nn) ? ncount[2 * t + 1] : 0;
    int p0 = (c0 + 3) & ~3, p1 = (c1 + 3) & ~3;
    int ps = p0 + p1;
    sc[t] = ps; __syncthreads();
    for (int off = 1; off < 256; off <<= 1) {
        int v = (t >= off) ? sc[t - off] : 0;
        __syncthreads();
        sc[t] += v;
        __syncthreads();
    }
    int ex = sc[t] - ps;
    if (2 * t < nn) nstart[2 * t] = ex;
    if (2 * t + 1 < nn) nstart[2 * t + 1] = ex + p0;
    __syncthreads();
    for (int i = t; i < nn; i += 256) {
        int node = node0 + i;
        int c = ncount[i];
        int pc = (c + 3) & ~3;
        int st = ebase + nstart[i];
        start[node] = st;
        counts[node] = pc;                        // padded count (tail uses DUMMY rows)
        dinv[node] = rsqrtf((float)(c + 1));
        for (int k = c; k < pc; ++k) csr4[st + k] = DUMMY;
    }
    __syncthreads();
    for (int i = t; i < cnt; i += 256) {
        unsigned r = sl[i];
        int pos = atomicAdd(&nstart[r >> 17], 1);
        csr4[ebase + pos] = r & 0x1ffffu;
    }
}

// -- h0 = x @ W_sgc + b_sgc: bf16 h0 (residual) + CHUNKED fp8 h0s (gathers) --
__global__ __launch_bounds__(256) void k_h0(const float* __restrict__ x,
        const float* __restrict__ W, const float* __restrict__ bias,
        const float* __restrict__ dinv,
        ushort_t* __restrict__ h0b, unsigned char* __restrict__ h0s) {
    int wid = (blockIdx.x * 256 + (int)threadIdx.x) >> 6;
    int lane = threadIdx.x & 63;
    if (wid >= N_NODES / 16) return;
    int row0 = wid * 16;
    int m = lane & 15, q = lane >> 4;

    frag_ab bfr[2][4];
#pragma unroll
    for (int ks = 0; ks < 2; ++ks)
#pragma unroll
        for (int nt = 0; nt < 4; ++nt)
#pragma unroll
            for (int j = 0; j < 8; ++j)
                bfr[ks][nt][j] = (short)f2bf(W[(ks * 32 + q * 8 + j) * 64 + nt * 16 + m]);

    frag_ab afr[2];
#pragma unroll
    for (int ks = 0; ks < 2; ++ks) {
        const float4* xp = (const float4*)(x + (size_t)(row0 + m) * 64 + ks * 32 + q * 8);
        float4 v0 = xp[0], v1 = xp[1];
        afr[ks][0] = (short)f2bf(v0.x); afr[ks][1] = (short)f2bf(v0.y);
        afr[ks][2] = (short)f2bf(v0.z); afr[ks][3] = (short)f2bf(v0.w);
        afr[ks][4] = (short)f2bf(v1.x); afr[ks][5] = (short)f2bf(v1.y);
        afr[ks][6] = (short)f2bf(v1.z); afr[ks][7] = (short)f2bf(v1.w);
    }

    frag_cd acc[4];
#pragma unroll
    for (int nt = 0; nt < 4; ++nt) acc[nt] = (frag_cd){0.f, 0.f, 0.f, 0.f};
#pragma unroll
    for (int ks = 0; ks < 2; ++ks)
#pragma unroll
        for (int nt = 0; nt < 4; ++nt)
            acc[nt] = __builtin_amdgcn_mfma_f32_16x16x32_bf16(afr[ks], bfr[ks][nt], acc[nt], 0, 0, 0);

    float dv[4];
#pragma unroll
    for (int r = 0; r < 4; ++r) dv[r] = dinv[row0 + q * 4 + r];

#pragma unroll
    for (int nt = 0; nt < 4; ++nt) {
        int cc = nt * 16 + m;
        float bl = bias[cc];
#pragma unroll
        for (int r = 0; r < 4; ++r) {
            int rr = row0 + q * 4 + r;
            float hv = acc[nt][r] + bl;
            h0b[(size_t)rr * 64 + cc] = f2bf(hv);
            // chunked: chunk nt, byte m of node rr
            h0s[((size_t)nt * NP1 + rr) * 16 + m] = f32_fp8(hv * dv[r]);
        }
    }
    if (wid == 0)   // dummy rows: 4 chunks x 16 B
        h0s[((size_t)(lane >> 4) * NP1 + N_NODES) * 16 + (lane & 15)] = 0;
}

// ------------- chunked hop: chunk = blockIdx&3, wave = 16 nodes x 4 lanes ---
// Each XCD (round-robin blockIdx%8) sees one chunk -> 1.6 MB gather set in L2.
__device__ __forceinline__ void hop_sum_c(int node, int j, int c,
        const unsigned char* __restrict__ hs_in,
        const int* __restrict__ start, const int* __restrict__ counts,
        const unsigned* __restrict__ csr4,
        float& a0, float& a1, float& a2, float& a3) {
    const unsigned* in_c = (const unsigned*)(hs_in + (size_t)c * NP1 * 16);
    int st = start[node], cnt = counts[node];
    int mx = cnt;
    mx = max(mx, __shfl_xor(mx, 4, 64));
    mx = max(mx, __shfl_xor(mx, 8, 64));
    mx = max(mx, __shfl_xor(mx, 16, 64));
    mx = max(mx, __shfl_xor(mx, 32, 64));
    unsigned g = in_c[(size_t)node * 4 + j];          // self
    floatx2 lo = fp8_lo2(g), hi = fp8_hi2(g);
    a0 = lo.x; a1 = lo.y; a2 = hi.x; a3 = hi.y;
    for (int e = 0; e < mx; ++e) {
        unsigned cidx = DUMMY;
        if (e < cnt) cidx = __builtin_nontemporal_load(csr4 + st + e);
        unsigned gg = in_c[(size_t)cidx * 4 + j];
        floatx2 l2 = fp8_lo2(gg), h2 = fp8_hi2(gg);
        a0 += l2.x; a1 += l2.y; a2 += h2.x; a3 += h2.y;
    }
}

__global__ __launch_bounds__(256) void k_hop_c(
        const unsigned char* __restrict__ hs_in, const unsigned char* __restrict__ hs0,
        const float* __restrict__ dinv, const int* __restrict__ start,
        const int* __restrict__ counts, const unsigned* __restrict__ csr4,
        unsigned char* __restrict__ hs_out) {
    int c = blockIdx.x & 3;
    if ((blockIdx.x >> 2) == 0 && threadIdx.x < 16)   // dummy row of this chunk
        hs_out[((size_t)c * NP1 + N_NODES) * 16 + threadIdx.x] = 0;
    int grp = (blockIdx.x >> 2) * 4 + (threadIdx.x >> 6);
    if (grp >= NGRP16) return;
    int lane = threadIdx.x & 63;
    int node = grp * 16 + (lane >> 2);
    int j = lane & 3;
    float a0, a1, a2, a3;
    hop_sum_c(node, j, c, hs_in, start, counts, csr4, a0, a1, a2, a3);
    float di = dinv[node];
    float k = 0.5f * di * di;
    unsigned r = __builtin_nontemporal_load(
        (const unsigned*)(hs0 + (size_t)c * NP1 * 16) + (size_t)node * 4 + j);
    floatx2 rl = fp8_lo2(r), rh = fp8_hi2(r);
    unsigned outw = f32_fp8x4(k * a0 + 0.5f * rl.x, k * a1 + 0.5f * rl.y,
                              k * a2 + 0.5f * rh.x, k * a3 + 0.5f * rh.y);
    ((unsigned*)(hs_out + (size_t)c * NP1 * 16))[(size_t)node * 4 + j] = outw;
}

// final hop: bf16 residual from h0b, relu, bf16 hfin out (no attention here)
__global__ __launch_bounds__(256) void k_hop_final_c(
        const unsigned char* __restrict__ hs_in, const ushort_t* __restrict__ h0b,
        const float* __restrict__ dinv, const int* __restrict__ start,
        const int* __restrict__ counts, const unsigned* __restrict__ csr4,
        ushort_t* __restrict__ hfin) {
    int c = blockIdx.x & 3;
    int grp = (blockIdx.x >> 2) * 4 + (threadIdx.x >> 6);
    if (grp >= NGRP16) return;
    int lane = threadIdx.x & 63;
    int node = grp * 16 + (lane >> 2);
    int j = lane & 3;
    float a0, a1, a2, a3;
    hop_sum_c(node, j, c, hs_in, start, counts, csr4, a0, a1, a2, a3);
    float di = dinv[node];
    uintx2 r2 = __builtin_nontemporal_load(
        (const uintx2*)(h0b + (size_t)node * 64 + c * 16 + j * 4));
    float h0v = fmaxf(0.5f * di * a0 + 0.5f * bf_lo(r2.x), 0.f);
    float h1v = fmaxf(0.5f * di * a1 + 0.5f * bf_hi(r2.x), 0.f);
    float h2v = fmaxf(0.5f * di * a2 + 0.5f * bf_lo(r2.y), 0.f);
    float h3v = fmaxf(0.5f * di * a3 + 0.5f * bf_hi(r2.y), 0.f);
    uintx2 o;
    o.x = pack2(h1v, h0v);
    o.y = pack2(h3v, h2v);
    __builtin_nontemporal_store(o, (uintx2*)(hfin + (size_t)node * 64 + c * 16 + j * 4));
}

// ------- readout + MLP head, one block per graph; computes v gate itself ----
__global__ void k_readout_mlp(const ushort_t* __restrict__ hb, float* __restrict__ v_raw,
        const int* __restrict__ gbound,
        const float* __restrict__ w_att, const float* __restrict__ b_att,
        const float* __restrict__ W1, const float* __restrict__ b1,
        const float* __restrict__ W2, const float* __restrict__ b2,
        const float* __restrict__ W3, const float* __restrict__ b3,
        float* __restrict__ out) {
    int g = blockIdx.x, t = threadIdx.x;
    int s = gbound[g], e = gbound[g + 1];
    __shared__ float red[256];
    int wv = t >> 6, lane = t & 63;

    // pass A: v = sigmoid(h . w_att + b_att) for this graph's nodes
    float wl = w_att[lane];
    float ba = b_att[0];
    for (int n = s + wv; n < e; n += 4) {
        float hv = bf2f(hb[(size_t)n * 64 + lane]);
        float p = hv * wl;
#pragma unroll
        for (int off = 32; off >= 1; off >>= 1) p += __shfl_xor(p, off, 64);
        if (lane == 0) v_raw[n] = 1.f / (1.f + expf(-(p + ba)));
    }
    __threadfence_block();
    __syncthreads();

    // segment max of v
    float m = -3.402823466e38f;
    for (int n = s + t; n < e; n += 256) m = fmaxf(m, v_raw[n]);
    red[t] = m; __syncthreads();
    for (int off = 128; off >= 1; off >>= 1) {
        if (t < off) red[t] = fmaxf(red[t], red[t + off]);
        __syncthreads();
    }
    float vmax = red[0]; __syncthreads();

    float ss = 0.f;
    for (int n = s + t; n < e; n += 256) ss += expf(v_raw[n] - vmax);
    red[t] = ss; __syncthreads();
    for (int off = 128; off >= 1; off >>= 1) {
        if (t < off) red[t] += red[t + off];
        __syncthreads();
    }
    float inv = 1.f / (red[0] + 1e-16f);
    __syncthreads();

    float gm = -3.402823466e38f, gs = 0.f;
    for (int n = s + wv; n < e; n += 4) {
        float hv = bf2f(hb[(size_t)n * 64 + lane]);
        float vn = expf(v_raw[n] - vmax) * inv;
        gm = fmaxf(gm, hv);
        gs += vn * hv;
    }
    __shared__ float pm[4][64], ps[4][64];
    pm[wv][lane] = gm; ps[wv][lane] = gs;
    __syncthreads();

    __shared__ float z[128];
    if (t < 64) {
        z[t] = fmaxf(fmaxf(pm[0][t], pm[1][t]), fmaxf(pm[2][t], pm[3][t]));
        z[64 + t] = ps[0][t] + ps[1][t] + ps[2][t] + ps[3][t];
    }
    __syncthreads();

    __shared__ float z1[64];
    if (t < 64) {
        float a = b1[t];
#pragma unroll 8
        for (int k = 0; k < 128; ++k) a += z[k] * W1[k * 64 + t];
        z1[t] = fmaxf(a, 0.f);
    }
    __syncthreads();
    __shared__ float z2[32];
    if (t < 32) {
        float a = b2[t];
#pragma unroll 8
        for (int k = 0; k < 64; ++k) a += z1[k] * W2[k * 32 + t];
        z2[t] = fmaxf(a, 0.f);
    }
    __syncthreads();
    __shared__ float z3[8];
    if (t < 8) {
        float a = b3[t];
#pragma unroll
        for (int k = 0; k < 32; ++k) a += z2[k] * W3[k * 8 + t];
        z3[t] = a;
    }
    __syncthreads();
    if (t == 0) {
        float mx = z3[0];
#pragma unroll
        for (int jj = 1; jj < 8; ++jj) mx = fmaxf(mx, z3[jj]);
        float se = 0.f;
#pragma unroll
        for (int jj = 0; jj < 8; ++jj) se += expf(z3[jj] - mx);
        float lse = mx + logf(se);
#pragma unroll
        for (int jj = 0; jj < 8; ++jj) out[g * 8 + jj] = z3[jj] - lse;
    }
}

extern "C" void kernel_launch(void* const* d_in, const int* in_sizes, int n_in,
                              void* d_out, int out_size, void* d_ws, size_t ws_size,
                              hipStream_t stream) {
    const float* x     = (const float*)d_in[0];
    const int*   edge  = (const int*)d_in[1];
    const int*   row   = edge;
    const int*   col   = edge + N_EDGES;
    const int*   batch = (const int*)d_in[2];
    const float* W_sgc = (const float*)d_in[3];
    const float* b_sgc = (const float*)d_in[4];
    const float* w_att = (const float*)d_in[5];
    const float* b_att = (const float*)d_in[6];
    const float* W1    = (const float*)d_in[7];
    const float* b1    = (const float*)d_in[8];
    const float* W2    = (const float*)d_in[9];
    const float* b2    = (const float*)d_in[10];
    const float* W3    = (const float*)d_in[11];
    const float* b3    = (const float*)d_in[12];
    float* out = (float*)d_out;

    char* p = (char*)d_ws;
    auto alloc = [&](size_t bytes) {
        char* r = p;
        p += (bytes + 255) & ~(size_t)255;
        return r;
    };
    int*      gcursor = (int*)alloc((size_t)NBUCK * 4);
    int*      gbound  = (int*)alloc((size_t)(NGRAPH + 1) * 4);
    int*      start   = (int*)alloc((size_t)N_NODES * 4);
    int*      counts  = (int*)alloc((size_t)N_NODES * 4);
    float*    dinv    = (float*)alloc((size_t)N_NODES * 4);
    float*    vraw    = (float*)alloc((size_t)N_NODES * 4);
    ushort_t* h0b     = (ushort_t*)alloc((size_t)N_NODES * 64 * 2);          // bf16
    unsigned char* h0sC = (unsigned char*)alloc((size_t)4 * NP1 * 16);       // fp8 chunked
    unsigned char* hAsC = (unsigned char*)alloc((size_t)4 * NP1 * 16);
    unsigned char* hBsC = (unsigned char*)alloc((size_t)4 * NP1 * 16);
    ushort_t* hfin    = (ushort_t*)alloc((size_t)N_NODES * 64 * 2);          // bf16 final h
    unsigned* csr4    = (unsigned*)alloc(((size_t)NBUCK * WINCAP + 64) * 4);
    unsigned* slab    = (unsigned*)alloc((size_t)NBUCK * BUCKCAP * 4);

    hipMemsetAsync(gcursor, 0, (size_t)NBUCK * 4, stream);

    k_binstage_bounds<<<NBIN_BLOCKS + NBOUND_BLOCKS, 256, 0, stream>>>(
        row, col, gcursor, slab, batch, gbound);
    k_bucket_build<<<NBUCK, 256, 0, stream>>>(slab, gcursor, start, counts, dinv, csr4);
    k_h0<<<(N_NODES / 16 + 3) / 4, 256, 0, stream>>>(x, W_sgc, b_sgc, dinv, h0b, h0sC);
    k_hop_c<<<HOP_BLOCKS, 256, 0, stream>>>(h0sC, h0sC, dinv, start, counts, csr4, hAsC);
    k_hop_c<<<HOP_BLOCKS, 256, 0, stream>>>(hAsC, h0sC, dinv, start, counts, csr4, hBsC);
    k_hop_final_c<<<HOP_BLOCKS, 256, 0, stream>>>(hBsC, h0b, dinv, start, counts, csr4, hfin);
    k_readout_mlp<<<NGRAPH, 256, 0, stream>>>(hfin, vraw, gbound, w_att, b_att,
                                              W1, b1, W2, b2, W3, b3, out);
}

// Round 14
// 276.044 us; speedup vs baseline: 1.6001x; 1.6001x over previous
//
#include <hip/hip_runtime.h>
#include <math.h>

#define N_NODES 100000
#define N_EDGES 1000000
#define NGRAPH 256

#define NBUCK 196          // ceil(100000 / 512)
#define BUCKN 512
#define BUCKCAP 8192       // max raw edges/bucket (mean ~5120, ~40 sigma margin)
#define EPB 4096           // edges per S1 block
#define NBIN_BLOCKS ((N_EDGES + EPB - 1) / EPB)          // 245
#define NBOUND_BLOCKS ((N_NODES + 255) / 256)            // 391
#define WINCAP 10240       // fixed csr window per bucket
#define DUMMY ((unsigned)N_NODES)   // pad col -> node with hs == 0

typedef unsigned short ushort_t;
typedef __attribute__((ext_vector_type(2))) float floatx2;
typedef __attribute__((ext_vector_type(4))) unsigned uintx4;

__device__ __forceinline__ ushort_t f2bf(float f) {   // round-to-nearest-even
    unsigned u = __float_as_uint(f);
    u += 0x7fffu + ((u >> 16) & 1u);
    return (ushort_t)(u >> 16);
}
__device__ __forceinline__ float bf2f(ushort_t u) {
    return __uint_as_float(((unsigned)u) << 16);
}
__device__ __forceinline__ float bf_lo(unsigned u) {
    return __uint_as_float(u << 16);
}
__device__ __forceinline__ float bf_hi(unsigned u) {
    return __uint_as_float(u & 0xffff0000u);
}
__device__ __forceinline__ unsigned pack2(float hi, float lo) {
    return ((unsigned)f2bf(hi) << 16) | (unsigned)f2bf(lo);
}
// fp8 e4m3 (OCP) HW converts, gfx950
__device__ __forceinline__ floatx2 fp8x2_f32(ushort_t u) {      // byte0 -> .x, byte1 -> .y
    return __builtin_amdgcn_cvt_pk_f32_fp8((unsigned)u, false);
}
__device__ __forceinline__ ushort_t f32_fp8x2(float a, float b) {
    return (ushort_t)(__builtin_amdgcn_cvt_pk_fp8_f32(a, b, 0u, false) & 0xffffu);
}
__device__ __forceinline__ unsigned char f32_fp8(float a) {
    return (unsigned char)(__builtin_amdgcn_cvt_pk_fp8_f32(a, 0.f, 0u, false) & 0xffu);
}

using frag_ab = __attribute__((ext_vector_type(8))) short;
using frag_cd = __attribute__((ext_vector_type(4))) float;

// ------ S1 fused: blocks [0,NBIN_BLOCKS) bin edges; rest do graph bounds ----
__global__ __launch_bounds__(256) void k_binstage_bounds(const int* __restrict__ row,
        const int* __restrict__ col, int* __restrict__ gcursor,
        unsigned* __restrict__ slab,
        const int* __restrict__ batch, int* __restrict__ gbound) {
    __shared__ int lcount[NBUCK];
    __shared__ int lbase[NBUCK];
    int t = threadIdx.x;
    if (blockIdx.x >= NBIN_BLOCKS) {
        int n = (blockIdx.x - NBIN_BLOCKS) * 256 + t;
        if (n >= N_NODES) return;
        int b = batch[n];
        int prev = (n == 0) ? -1 : batch[n - 1];
        for (int g = prev + 1; g <= b; ++g) gbound[g] = n;
        if (n == N_NODES - 1) {
            for (int g = b + 1; g <= NGRAPH; ++g) gbound[g] = N_NODES;
        }
        return;
    }
    for (int i = t; i < NBUCK; i += 256) lcount[i] = 0;
    __syncthreads();
    int base = blockIdx.x * EPB;
    unsigned rec[16]; int bp[16];
#pragma unroll
    for (int k = 0; k < 16; ++k) {
        int e = base + k * 256 + t;
        if (e < N_EDGES) {
            int r = row[e], c = col[e];
            int b = r >> 9;
            int pos = atomicAdd(&lcount[b], 1);
            rec[k] = ((unsigned)(r & 511) << 17) | (unsigned)c;
            bp[k] = (b << 16) | pos;
        } else bp[k] = -1;
    }
    __syncthreads();
    for (int b = t; b < NBUCK; b += 256) {
        int c = lcount[b];
        lbase[b] = (c > 0) ? atomicAdd(&gcursor[b], c) : 0;
    }
    __syncthreads();
#pragma unroll
    for (int k = 0; k < 16; ++k) {
        if (bp[k] >= 0) {
            int b = bp[k] >> 16, pos = bp[k] & 0xffff;
            slab[(size_t)b * BUCKCAP + lbase[b] + pos] = rec[k];
        }
    }
}

// ------ S2: per-bucket CSR build into FIXED window b*WINCAP, pad-to-4 -------
__global__ __launch_bounds__(256) void k_bucket_build(const unsigned* __restrict__ slab,
        const int* __restrict__ gcursor,
        int* __restrict__ start, int* __restrict__ counts, float* __restrict__ dinv,
        unsigned* __restrict__ csr4) {
    __shared__ int ncount[BUCKN];
    __shared__ int nstart[BUCKN];
    __shared__ int sc[256];
    int b = blockIdx.x, t = threadIdx.x;
    int cnt = gcursor[b];
    int ebase = b * WINCAP;
    int node0 = b * BUCKN;
    int nn = min(BUCKN, N_NODES - node0);
    for (int i = t; i < nn; i += 256) ncount[i] = 0;
    __syncthreads();
    const unsigned* sl = slab + (size_t)b * BUCKCAP;
    for (int i = t; i < cnt; i += 256)
        atomicAdd(&ncount[sl[i] >> 17], 1);
    __syncthreads();
    int c0 = (2 * t < nn) ? ncount[2 * t] : 0;
    int c1 = (2 * t + 1 < nn) ? ncount[2 * t + 1] : 0;
    int p0 = (c0 + 3) & ~3, p1 = (c1 + 3) & ~3;
    int ps = p0 + p1;
    sc[t] = ps; __syncthreads();
    for (int off = 1; off < 256; off <<= 1) {
        int v = (t >= off) ? sc[t - off] : 0;
        __syncthreads();
        sc[t] += v;
        __syncthreads();
    }
    int ex = sc[t] - ps;
    if (2 * t < nn) nstart[2 * t] = ex;
    if (2 * t + 1 < nn) nstart[2 * t + 1] = ex + p0;
    __syncthreads();
    for (int i = t; i < nn; i += 256) {
        int node = node0 + i;
        int c = ncount[i];
        int pc = (c + 3) & ~3;
        int st = ebase + nstart[i];
        start[node] = st;
        counts[node] = pc;                        // PADDED count for the hop
        dinv[node] = rsqrtf((float)(c + 1));      // true degree for normalization
        for (int k = c; k < pc; ++k) csr4[st + k] = DUMMY;
    }
    __syncthreads();
    for (int i = t; i < cnt; i += 256) {
        unsigned r = sl[i];
        int pos = atomicAdd(&nstart[r >> 17], 1);
        csr4[ebase + pos] = r & 0x1ffffu;
    }
}

// ------- h0 = x @ W_sgc + b_sgc: bf16 h0 (residual) + fp8 h0s (gathers) -----
__global__ __launch_bounds__(256) void k_h0(const float* __restrict__ x,
        const float* __restrict__ W, const float* __restrict__ bias,
        const float* __restrict__ dinv,
        ushort_t* __restrict__ h0b, unsigned char* __restrict__ h0s) {
    int wid = (blockIdx.x * 256 + (int)threadIdx.x) >> 6;
    int lane = threadIdx.x & 63;
    if (wid >= N_NODES / 16) return;
    int row0 = wid * 16;
    int m = lane & 15, q = lane >> 4;

    frag_ab bfr[2][4];
#pragma unroll
    for (int ks = 0; ks < 2; ++ks)
#pragma unroll
        for (int nt = 0; nt < 4; ++nt)
#pragma unroll
            for (int j = 0; j < 8; ++j)
                bfr[ks][nt][j] = (short)f2bf(W[(ks * 32 + q * 8 + j) * 64 + nt * 16 + m]);

    frag_ab afr[2];
#pragma unroll
    for (int ks = 0; ks < 2; ++ks) {
        const float4* xp = (const float4*)(x + (size_t)(row0 + m) * 64 + ks * 32 + q * 8);
        float4 v0 = xp[0], v1 = xp[1];
        afr[ks][0] = (short)f2bf(v0.x); afr[ks][1] = (short)f2bf(v0.y);
        afr[ks][2] = (short)f2bf(v0.z); afr[ks][3] = (short)f2bf(v0.w);
        afr[ks][4] = (short)f2bf(v1.x); afr[ks][5] = (short)f2bf(v1.y);
        afr[ks][6] = (short)f2bf(v1.z); afr[ks][7] = (short)f2bf(v1.w);
    }

    frag_cd acc[4];
#pragma unroll
    for (int nt = 0; nt < 4; ++nt) acc[nt] = (frag_cd){0.f, 0.f, 0.f, 0.f};
#pragma unroll
    for (int ks = 0; ks < 2; ++ks)
#pragma unroll
        for (int nt = 0; nt < 4; ++nt)
            acc[nt] = __builtin_amdgcn_mfma_f32_16x16x32_bf16(afr[ks], bfr[ks][nt], acc[nt], 0, 0, 0);

    float dv[4];
#pragma unroll
    for (int r = 0; r < 4; ++r) dv[r] = dinv[row0 + q * 4 + r];

#pragma unroll
    for (int nt = 0; nt < 4; ++nt) {
        int cc = nt * 16 + m;
        float bl = bias[cc];
#pragma unroll
        for (int r = 0; r < 4; ++r) {
            int rr = row0 + q * 4 + r;
            float hv = acc[nt][r] + bl;
            h0b[(size_t)rr * 64 + cc] = f2bf(hv);
            h0s[(size_t)rr * 64 + cc] = f32_fp8(hv * dv[r]);   // byte store
        }
    }
    if (wid == 0) h0s[(size_t)N_NODES * 64 + lane] = 0;   // dummy row = 0
}

// -------- hop inner sum: 2 nodes/wave, nt-uint4 csr, fp8 gathers ------------
// lane l handles features 2l, 2l+1 (one fp8 pair = ushort).
__device__ __forceinline__ void hop_sum(int node, int l,
        const ushort_t* __restrict__ hs_in, const int* __restrict__ start,
        const int* __restrict__ counts, const unsigned* __restrict__ csr4,
        float& a0, float& a1) {
    floatx2 s = fp8x2_f32(hs_in[node * 32 + l]);   // self-loop term (hs form)
    a0 = s.x; a1 = s.y;
    int st = start[node], cnt = counts[node];      // cnt % 4 == 0, st 16B-aligned
    for (int j = 0; j < cnt; j += 4) {
        // csr is a once-per-hop 4MB stream: nontemporal keeps it from evicting
        // the hs gather set in L2
        uintx4 cc = __builtin_nontemporal_load((const uintx4*)(csr4 + st + j));
        ushort_t u0 = hs_in[cc.x * 32 + l];
        ushort_t u1 = hs_in[cc.y * 32 + l];
        ushort_t u2 = hs_in[cc.z * 32 + l];
        ushort_t u3 = hs_in[cc.w * 32 + l];
        floatx2 f0 = fp8x2_f32(u0);
        floatx2 f1 = fp8x2_f32(u1);
        floatx2 f2 = fp8x2_f32(u2);
        floatx2 f3 = fp8x2_f32(u3);
        a0 += f0.x; a1 += f0.y;
        a0 += f1.x; a1 += f1.y;
        a0 += f2.x; a1 += f2.y;
        a0 += f3.x; a1 += f3.y;
    }
}

// intermediate hop: residual from hs0 (fp8), writes fp8 hs_out:
//   hs_{k+1} = dinv * h_{k+1} = 0.5*di^2*S + 0.5*hs0
__global__ void k_hop(const ushort_t* __restrict__ hs_in, const ushort_t* __restrict__ hs0,
                      const float* __restrict__ dinv, const int* __restrict__ start,
                      const int* __restrict__ counts, const unsigned* __restrict__ csr4,
                      ushort_t* __restrict__ hs_out) {
    int node = blockIdx.x * 8 + ((int)threadIdx.x >> 5);   // N_NODES % 8 == 0
    int l = threadIdx.x & 31;
    float a0, a1;
    hop_sum(node, l, hs_in, start, counts, csr4, a0, a1);
    float di = dinv[node];
    float c = 0.5f * di * di;
    floatx2 r0 = fp8x2_f32(hs0[node * 32 + l]);
    float s0 = c * a0 + 0.5f * r0.x;
    float s1 = c * a1 + 0.5f * r0.y;
    hs_out[node * 32 + l] = f32_fp8x2(s0, s1);
    if (blockIdx.x == 0 && threadIdx.x < 32)
        hs_out[N_NODES * 32 + threadIdx.x] = 0;           // dummy row = 0
}

// final hop: plain bf16 h out (relu, residual from bf16 h0b) + attention gate
__global__ void k_hop_final(const ushort_t* __restrict__ hs_in, const unsigned* __restrict__ h0b,
                            const float* __restrict__ dinv, const int* __restrict__ start,
                            const int* __restrict__ counts, const unsigned* __restrict__ csr4,
                            const float* __restrict__ w_att, const float* __restrict__ b_att,
                            unsigned* __restrict__ h_out, float* __restrict__ v_raw) {
    int node = blockIdx.x * 8 + ((int)threadIdx.x >> 5);
    int l = threadIdx.x & 31;
    float a0, a1;
    hop_sum(node, l, hs_in, start, counts, csr4, a0, a1);
    float di = dinv[node];
    unsigned u0 = h0b[node * 32 + l];
    float h0v = fmaxf(0.5f * di * a0 + 0.5f * bf_lo(u0), 0.f);
    float h1v = fmaxf(0.5f * di * a1 + 0.5f * bf_hi(u0), 0.f);
    h_out[node * 32 + l] = pack2(h1v, h0v);
    float2 wa = *(const float2*)(w_att + 2 * l);
    float p = h0v * wa.x + h1v * wa.y;
#pragma unroll
    for (int off = 16; off >= 1; off >>= 1) p += __shfl_xor(p, off, 64);
    if (l == 0) {
        v_raw[node] = 1.f / (1.f + expf(-(p + b_att[0])));
    }
}

// ---------------- readout + MLP head, one block per graph ----------------
__global__ void k_readout_mlp(const ushort_t* __restrict__ hb, const float* __restrict__ v_raw,
        const int* __restrict__ gbound,
        const float* __restrict__ W1, const float* __restrict__ b1,
        const float* __restrict__ W2, const float* __restrict__ b2,
        const float* __restrict__ W3, const float* __restrict__ b3,
        float* __restrict__ out) {
    int g = blockIdx.x, t = threadIdx.x;
    int s = gbound[g], e = gbound[g + 1];
    __shared__ float red[256];

    float m = -3.402823466e38f;
    for (int n = s + t; n < e; n += 256) m = fmaxf(m, v_raw[n]);
    red[t] = m; __syncthreads();
    for (int off = 128; off >= 1; off >>= 1) {
        if (t < off) red[t] = fmaxf(red[t], red[t + off]);
        __syncthreads();
    }
    float vmax = red[0]; __syncthreads();

    float ss = 0.f;
    for (int n = s + t; n < e; n += 256) ss += expf(v_raw[n] - vmax);
    red[t] = ss; __syncthreads();
    for (int off = 128; off >= 1; off >>= 1) {
        if (t < off) red[t] += red[t + off];
        __syncthreads();
    }
    float inv = 1.f / (red[0] + 1e-16f);
    __syncthreads();

    int wv = t >> 6, lane = t & 63;
    float gm = -3.402823466e38f, gs = 0.f;
    for (int n = s + wv; n < e; n += 4) {
        float hv = bf2f(hb[(size_t)n * 64 + lane]);
        float vn = expf(v_raw[n] - vmax) * inv;
        gm = fmaxf(gm, hv);
        gs += vn * hv;
    }
    __shared__ float pm[4][64], ps[4][64];
    pm[wv][lane] = gm; ps[wv][lane] = gs;
    __syncthreads();

    __shared__ float z[128];
    if (t < 64) {
        z[t] = fmaxf(fmaxf(pm[0][t], pm[1][t]), fmaxf(pm[2][t], pm[3][t]));
        z[64 + t] = ps[0][t] + ps[1][t] + ps[2][t] + ps[3][t];
    }
    __syncthreads();

    __shared__ float z1[64];
    if (t < 64) {
        float a = b1[t];
#pragma unroll 8
        for (int k = 0; k < 128; ++k) a += z[k] * W1[k * 64 + t];
        z1[t] = fmaxf(a, 0.f);
    }
    __syncthreads();
    __shared__ float z2[32];
    if (t < 32) {
        float a = b2[t];
#pragma unroll 8
        for (int k = 0; k < 64; ++k) a += z1[k] * W2[k * 32 + t];
        z2[t] = fmaxf(a, 0.f);
    }
    __syncthreads();
    __shared__ float z3[8];
    if (t < 8) {
        float a = b3[t];
#pragma unroll
        for (int k = 0; k < 32; ++k) a += z2[k] * W3[k * 8 + t];
        z3[t] = a;
    }
    __syncthreads();
    if (t == 0) {
        float mx = z3[0];
#pragma unroll
        for (int j = 1; j < 8; ++j) mx = fmaxf(mx, z3[j]);
        float se = 0.f;
#pragma unroll
        for (int j = 0; j < 8; ++j) se += expf(z3[j] - mx);
        float lse = mx + logf(se);
#pragma unroll
        for (int j = 0; j < 8; ++j) out[g * 8 + j] = z3[j] - lse;
    }
}

extern "C" void kernel_launch(void* const* d_in, const int* in_sizes, int n_in,
                              void* d_out, int out_size, void* d_ws, size_t ws_size,
                              hipStream_t stream) {
    const float* x     = (const float*)d_in[0];
    const int*   edge  = (const int*)d_in[1];
    const int*   row   = edge;
    const int*   col   = edge + N_EDGES;
    const int*   batch = (const int*)d_in[2];
    const float* W_sgc = (const float*)d_in[3];
    const float* b_sgc = (const float*)d_in[4];
    const float* w_att = (const float*)d_in[5];
    const float* b_att = (const float*)d_in[6];
    const float* W1    = (const float*)d_in[7];
    const float* b1    = (const float*)d_in[8];
    const float* W2    = (const float*)d_in[9];
    const float* b2    = (const float*)d_in[10];
    const float* W3    = (const float*)d_in[11];
    const float* b3    = (const float*)d_in[12];
    float* out = (float*)d_out;

    char* p = (char*)d_ws;
    auto alloc = [&](size_t bytes) {
        char* r = p;
        p += (bytes + 255) & ~(size_t)255;
        return r;
    };
    int*      gcursor = (int*)alloc((size_t)NBUCK * 4);
    int*      gbound  = (int*)alloc((size_t)(NGRAPH + 1) * 4);
    int*      start   = (int*)alloc((size_t)N_NODES * 4);
    int*      counts  = (int*)alloc((size_t)N_NODES * 4);
    float*    dinv    = (float*)alloc((size_t)N_NODES * 4);
    float*    vraw    = (float*)alloc((size_t)N_NODES * 4);
    ushort_t* h0b     = (ushort_t*)alloc((size_t)N_NODES * 64 * 2);          // bf16
    unsigned char* h0s = (unsigned char*)alloc((size_t)(N_NODES + 1) * 64);  // fp8
    ushort_t* hAs     = (ushort_t*)alloc((size_t)(N_NODES + 1) * 32 * 2);    // fp8
    ushort_t* hBs     = (ushort_t*)alloc((size_t)(N_NODES + 1) * 32 * 2);    // fp8
    ushort_t* hfin    = (ushort_t*)alloc((size_t)N_NODES * 64 * 2);          // bf16 final h
    unsigned* csr4    = (unsigned*)alloc(((size_t)NBUCK * WINCAP + 64) * 4); // fixed windows
    unsigned* slab    = (unsigned*)alloc((size_t)NBUCK * BUCKCAP * 4);

    hipMemsetAsync(gcursor, 0, (size_t)NBUCK * 4, stream);

    k_binstage_bounds<<<NBIN_BLOCKS + NBOUND_BLOCKS, 256, 0, stream>>>(
        row, col, gcursor, slab, batch, gbound);
    k_bucket_build<<<NBUCK, 256, 0, stream>>>(slab, gcursor, start, counts, dinv, csr4);
    k_h0<<<(N_NODES / 16 + 3) / 4, 256, 0, stream>>>(x, W_sgc, b_sgc, dinv, h0b, h0s);
    k_hop<<<N_NODES / 8, 256, 0, stream>>>((const ushort_t*)h0s, (const ushort_t*)h0s,
                                           dinv, start, counts, csr4, hAs);
    k_hop<<<N_NODES / 8, 256, 0, stream>>>(hAs, (const ushort_t*)h0s,
                                           dinv, start, counts, csr4, hBs);
    k_hop_final<<<N_NODES / 8, 256, 0, stream>>>(hBs, (const unsigned*)h0b,
                                                 dinv, start, counts, csr4,
                                                 w_att, b_att, (unsigned*)hfin, vraw);
    k_readout_mlp<<<NGRAPH, 256, 0, stream>>>(hfin, vraw, gbound,
                                              W1, b1, W2, b2, W3, b3, out);
}

// Round 15
// 258.417 us; speedup vs baseline: 1.7092x; 1.0682x over previous
//
#include <hip/hip_runtime.h>
#include <math.h>

#define N_NODES 100000
#define N_EDGES 1000000
#define NGRAPH 256

#define NBUCK 196          // ceil(100000 / 512)
#define BUCKN 512
#define BUCKCAP 8192       // max raw edges/bucket (mean ~5120, ~40 sigma margin)
#define EPB 4096           // edges per S1 block
#define NBIN_BLOCKS ((N_EDGES + EPB - 1) / EPB)          // 245
#define NBOUND_BLOCKS ((N_NODES + 255) / 256)            // 391
#define WINCAP 10240       // fixed csr window per bucket
#define DUMMY ((unsigned)N_NODES)   // pad col -> node with hs == 0

typedef unsigned short ushort_t;
typedef __attribute__((ext_vector_type(2))) float floatx2;

__device__ __forceinline__ ushort_t f2bf(float f) {   // round-to-nearest-even
    unsigned u = __float_as_uint(f);
    u += 0x7fffu + ((u >> 16) & 1u);
    return (ushort_t)(u >> 16);
}
__device__ __forceinline__ float bf2f(ushort_t u) {
    return __uint_as_float(((unsigned)u) << 16);
}
__device__ __forceinline__ float bf_lo(unsigned u) {
    return __uint_as_float(u << 16);
}
__device__ __forceinline__ float bf_hi(unsigned u) {
    return __uint_as_float(u & 0xffff0000u);
}
__device__ __forceinline__ unsigned pack2(float hi, float lo) {
    return ((unsigned)f2bf(hi) << 16) | (unsigned)f2bf(lo);
}
// fp8 e4m3 (OCP) HW converts, gfx950
__device__ __forceinline__ floatx2 fp8x2_f32(ushort_t u) {      // byte0 -> .x, byte1 -> .y
    return __builtin_amdgcn_cvt_pk_f32_fp8((unsigned)u, false);
}
__device__ __forceinline__ ushort_t f32_fp8x2(float a, float b) {
    return (ushort_t)(__builtin_amdgcn_cvt_pk_fp8_f32(a, b, 0u, false) & 0xffffu);
}
__device__ __forceinline__ unsigned char f32_fp8(float a) {
    return (unsigned char)(__builtin_amdgcn_cvt_pk_fp8_f32(a, 0.f, 0u, false) & 0xffu);
}

using frag_ab = __attribute__((ext_vector_type(8))) short;
using frag_cd = __attribute__((ext_vector_type(4))) float;

// ------ S1 fused: blocks [0,NBIN_BLOCKS) bin edges; rest do graph bounds ----
__global__ __launch_bounds__(256) void k_binstage_bounds(const int* __restrict__ row,
        const int* __restrict__ col, int* __restrict__ gcursor,
        unsigned* __restrict__ slab,
        const int* __restrict__ batch, int* __restrict__ gbound) {
    __shared__ int lcount[NBUCK];
    __shared__ int lbase[NBUCK];
    int t = threadIdx.x;
    if (blockIdx.x >= NBIN_BLOCKS) {
        int n = (blockIdx.x - NBIN_BLOCKS) * 256 + t;
        if (n >= N_NODES) return;
        int b = batch[n];
        int prev = (n == 0) ? -1 : batch[n - 1];
        for (int g = prev + 1; g <= b; ++g) gbound[g] = n;
        if (n == N_NODES - 1) {
            for (int g = b + 1; g <= NGRAPH; ++g) gbound[g] = N_NODES;
        }
        return;
    }
    for (int i = t; i < NBUCK; i += 256) lcount[i] = 0;
    __syncthreads();
    int base = blockIdx.x * EPB;
    unsigned rec[16]; int bp[16];
#pragma unroll
    for (int k = 0; k < 16; ++k) {
        int e = base + k * 256 + t;
        if (e < N_EDGES) {
            int r = row[e], c = col[e];
            int b = r >> 9;
            int pos = atomicAdd(&lcount[b], 1);
            rec[k] = ((unsigned)(r & 511) << 17) | (unsigned)c;
            bp[k] = (b << 16) | pos;
        } else bp[k] = -1;
    }
    __syncthreads();
    for (int b = t; b < NBUCK; b += 256) {
        int c = lcount[b];
        lbase[b] = (c > 0) ? atomicAdd(&gcursor[b], c) : 0;
    }
    __syncthreads();
#pragma unroll
    for (int k = 0; k < 16; ++k) {
        if (bp[k] >= 0) {
            int b = bp[k] >> 16, pos = bp[k] & 0xffff;
            slab[(size_t)b * BUCKCAP + lbase[b] + pos] = rec[k];
        }
    }
}

// ------ S2: per-bucket CSR build into FIXED window b*WINCAP, pad-to-4 -------
__global__ __launch_bounds__(256) void k_bucket_build(const unsigned* __restrict__ slab,
        const int* __restrict__ gcursor,
        int* __restrict__ start, int* __restrict__ counts, float* __restrict__ dinv,
        unsigned* __restrict__ csr4) {
    __shared__ int ncount[BUCKN];
    __shared__ int nstart[BUCKN];
    __shared__ int sc[256];
    int b = blockIdx.x, t = threadIdx.x;
    int cnt = gcursor[b];
    int ebase = b * WINCAP;
    int node0 = b * BUCKN;
    int nn = min(BUCKN, N_NODES - node0);
    for (int i = t; i < nn; i += 256) ncount[i] = 0;
    __syncthreads();
    const unsigned* sl = slab + (size_t)b * BUCKCAP;
    for (int i = t; i < cnt; i += 256)
        atomicAdd(&ncount[sl[i] >> 17], 1);
    __syncthreads();
    int c0 = (2 * t < nn) ? ncount[2 * t] : 0;
    int c1 = (2 * t + 1 < nn) ? ncount[2 * t + 1] : 0;
    int p0 = (c0 + 3) & ~3, p1 = (c1 + 3) & ~3;
    int ps = p0 + p1;
    sc[t] = ps; __syncthreads();
    for (int off = 1; off < 256; off <<= 1) {
        int v = (t >= off) ? sc[t - off] : 0;
        __syncthreads();
        sc[t] += v;
        __syncthreads();
    }
    int ex = sc[t] - ps;
    if (2 * t < nn) nstart[2 * t] = ex;
    if (2 * t + 1 < nn) nstart[2 * t + 1] = ex + p0;
    __syncthreads();
    for (int i = t; i < nn; i += 256) {
        int node = node0 + i;
        int c = ncount[i];
        int pc = (c + 3) & ~3;
        int st = ebase + nstart[i];
        start[node] = st;
        counts[node] = pc;                        // PADDED count for the hop
        dinv[node] = rsqrtf((float)(c + 1));      // true degree for normalization
        for (int k = c; k < pc; ++k) csr4[st + k] = DUMMY;
    }
    __syncthreads();
    for (int i = t; i < cnt; i += 256) {
        unsigned r = sl[i];
        int pos = atomicAdd(&nstart[r >> 17], 1);
        csr4[ebase + pos] = r & 0x1ffffu;
    }
}

// ------- h0 = x @ W_sgc + b_sgc: bf16 h0 (residual) + fp8 h0s (gathers) -----
__global__ __launch_bounds__(256) void k_h0(const float* __restrict__ x,
        const float* __restrict__ W, const float* __restrict__ bias,
        const float* __restrict__ dinv,
        ushort_t* __restrict__ h0b, unsigned char* __restrict__ h0s) {
    int wid = (blockIdx.x * 256 + (int)threadIdx.x) >> 6;
    int lane = threadIdx.x & 63;
    if (wid >= N_NODES / 16) return;
    int row0 = wid * 16;
    int m = lane & 15, q = lane >> 4;

    frag_ab bfr[2][4];
#pragma unroll
    for (int ks = 0; ks < 2; ++ks)
#pragma unroll
        for (int nt = 0; nt < 4; ++nt)
#pragma unroll
            for (int j = 0; j < 8; ++j)
                bfr[ks][nt][j] = (short)f2bf(W[(ks * 32 + q * 8 + j) * 64 + nt * 16 + m]);

    frag_ab afr[2];
#pragma unroll
    for (int ks = 0; ks < 2; ++ks) {
        const float4* xp = (const float4*)(x + (size_t)(row0 + m) * 64 + ks * 32 + q * 8);
        float4 v0 = xp[0], v1 = xp[1];
        afr[ks][0] = (short)f2bf(v0.x); afr[ks][1] = (short)f2bf(v0.y);
        afr[ks][2] = (short)f2bf(v0.z); afr[ks][3] = (short)f2bf(v0.w);
        afr[ks][4] = (short)f2bf(v1.x); afr[ks][5] = (short)f2bf(v1.y);
        afr[ks][6] = (short)f2bf(v1.z); afr[ks][7] = (short)f2bf(v1.w);
    }

    frag_cd acc[4];
#pragma unroll
    for (int nt = 0; nt < 4; ++nt) acc[nt] = (frag_cd){0.f, 0.f, 0.f, 0.f};
#pragma unroll
    for (int ks = 0; ks < 2; ++ks)
#pragma unroll
        for (int nt = 0; nt < 4; ++nt)
            acc[nt] = __builtin_amdgcn_mfma_f32_16x16x32_bf16(afr[ks], bfr[ks][nt], acc[nt], 0, 0, 0);

    float dv[4];
#pragma unroll
    for (int r = 0; r < 4; ++r) dv[r] = dinv[row0 + q * 4 + r];

#pragma unroll
    for (int nt = 0; nt < 4; ++nt) {
        int cc = nt * 16 + m;
        float bl = bias[cc];
#pragma unroll
        for (int r = 0; r < 4; ++r) {
            int rr = row0 + q * 4 + r;
            float hv = acc[nt][r] + bl;
            h0b[(size_t)rr * 64 + cc] = f2bf(hv);
            h0s[(size_t)rr * 64 + cc] = f32_fp8(hv * dv[r]);   // byte store
        }
    }
    if (wid == 0) h0s[(size_t)N_NODES * 64 + lane] = 0;   // dummy row = 0
}

// -------- hop inner sum: 2 nodes/wave, uint4 csr, fp8 gathers (64B rows) ----
// lane l handles features 2l, 2l+1 (one fp8 pair = ushort).
__device__ __forceinline__ void hop_sum(int node, int l,
        const ushort_t* __restrict__ hs_in, const int* __restrict__ start,
        const int* __restrict__ counts, const unsigned* __restrict__ csr4,
        float& a0, float& a1) {
    floatx2 s = fp8x2_f32(hs_in[node * 32 + l]);   // self-loop term (hs form)
    a0 = s.x; a1 = s.y;
    int st = start[node], cnt = counts[node];      // cnt % 4 == 0, st 16B-aligned
    for (int j = 0; j < cnt; j += 4) {
        uint4 cc = *(const uint4*)(csr4 + st + j);   // broadcast, addr-independent
        ushort_t u0 = hs_in[cc.x * 32 + l];
        ushort_t u1 = hs_in[cc.y * 32 + l];
        ushort_t u2 = hs_in[cc.z * 32 + l];
        ushort_t u3 = hs_in[cc.w * 32 + l];
        floatx2 f0 = fp8x2_f32(u0);
        floatx2 f1 = fp8x2_f32(u1);
        floatx2 f2 = fp8x2_f32(u2);
        floatx2 f3 = fp8x2_f32(u3);
        a0 += f0.x; a1 += f0.y;
        a0 += f1.x; a1 += f1.y;
        a0 += f2.x; a1 += f2.y;
        a0 += f3.x; a1 += f3.y;
    }
}

// intermediate hop: residual from hs0 (fp8), writes fp8 hs_out:
//   hs_{k+1} = dinv * h_{k+1} = 0.5*di^2*S + 0.5*hs0
__global__ void k_hop(const ushort_t* __restrict__ hs_in, const ushort_t* __restrict__ hs0,
                      const float* __restrict__ dinv, const int* __restrict__ start,
                      const int* __restrict__ counts, const unsigned* __restrict__ csr4,
                      ushort_t* __restrict__ hs_out) {
    int node = blockIdx.x * 8 + ((int)threadIdx.x >> 5);   // N_NODES % 8 == 0
    int l = threadIdx.x & 31;
    float a0, a1;
    hop_sum(node, l, hs_in, start, counts, csr4, a0, a1);
    float di = dinv[node];
    float c = 0.5f * di * di;
    floatx2 r0 = fp8x2_f32(hs0[node * 32 + l]);
    float s0 = c * a0 + 0.5f * r0.x;
    float s1 = c * a1 + 0.5f * r0.y;
    hs_out[node * 32 + l] = f32_fp8x2(s0, s1);
    if (blockIdx.x == 0 && threadIdx.x < 32)
        hs_out[N_NODES * 32 + threadIdx.x] = 0;           // dummy row = 0
}

// final hop: plain bf16 h out (relu, residual from bf16 h0b) + attention gate
__global__ void k_hop_final(const ushort_t* __restrict__ hs_in, const unsigned* __restrict__ h0b,
                            const float* __restrict__ dinv, const int* __restrict__ start,
                            const int* __restrict__ counts, const unsigned* __restrict__ csr4,
                            const float* __restrict__ w_att, const float* __restrict__ b_att,
                            unsigned* __restrict__ h_out, float* __restrict__ v_raw) {
    int node = blockIdx.x * 8 + ((int)threadIdx.x >> 5);
    int l = threadIdx.x & 31;
    float a0, a1;
    hop_sum(node, l, hs_in, start, counts, csr4, a0, a1);
    float di = dinv[node];
    unsigned u0 = h0b[node * 32 + l];
    float h0v = fmaxf(0.5f * di * a0 + 0.5f * bf_lo(u0), 0.f);
    float h1v = fmaxf(0.5f * di * a1 + 0.5f * bf_hi(u0), 0.f);
    h_out[node * 32 + l] = pack2(h1v, h0v);
    float2 wa = *(const float2*)(w_att + 2 * l);
    float p = h0v * wa.x + h1v * wa.y;
#pragma unroll
    for (int off = 16; off >= 1; off >>= 1) p += __shfl_xor(p, off, 64);
    if (l == 0) {
        v_raw[node] = 1.f / (1.f + expf(-(p + b_att[0])));
    }
}

// ---------------- readout + MLP head, one block per graph ----------------
__global__ void k_readout_mlp(const ushort_t* __restrict__ hb, const float* __restrict__ v_raw,
        const int* __restrict__ gbound,
        const float* __restrict__ W1, const float* __restrict__ b1,
        const float* __restrict__ W2, const float* __restrict__ b2,
        const float* __restrict__ W3, const float* __restrict__ b3,
        float* __restrict__ out) {
    int g = blockIdx.x, t = threadIdx.x;
    int s = gbound[g], e = gbound[g + 1];
    __shared__ float red[256];

    float m = -3.402823466e38f;
    for (int n = s + t; n < e; n += 256) m = fmaxf(m, v_raw[n]);
    red[t] = m; __syncthreads();
    for (int off = 128; off >= 1; off >>= 1) {
        if (t < off) red[t] = fmaxf(red[t], red[t + off]);
        __syncthreads();
    }
    float vmax = red[0]; __syncthreads();

    float ss = 0.f;
    for (int n = s + t; n < e; n += 256) ss += expf(v_raw[n] - vmax);
    red[t] = ss; __syncthreads();
    for (int off = 128; off >= 1; off >>= 1) {
        if (t < off) red[t] += red[t + off];
        __syncthreads();
    }
    float inv = 1.f / (red[0] + 1e-16f);
    __syncthreads();

    int wv = t >> 6, lane = t & 63;
    float gm = -3.402823466e38f, gs = 0.f;
    for (int n = s + wv; n < e; n += 4) {
        float hv = bf2f(hb[(size_t)n * 64 + lane]);
        float vn = expf(v_raw[n] - vmax) * inv;
        gm = fmaxf(gm, hv);
        gs += vn * hv;
    }
    __shared__ float pm[4][64], ps[4][64];
    pm[wv][lane] = gm; ps[wv][lane] = gs;
    __syncthreads();

    __shared__ float z[128];
    if (t < 64) {
        z[t] = fmaxf(fmaxf(pm[0][t], pm[1][t]), fmaxf(pm[2][t], pm[3][t]));
        z[64 + t] = ps[0][t] + ps[1][t] + ps[2][t] + ps[3][t];
    }
    __syncthreads();

    __shared__ float z1[64];
    if (t < 64) {
        float a = b1[t];
#pragma unroll 8
        for (int k = 0; k < 128; ++k) a += z[k] * W1[k * 64 + t];
        z1[t] = fmaxf(a, 0.f);
    }
    __syncthreads();
    __shared__ float z2[32];
    if (t < 32) {
        float a = b2[t];
#pragma unroll 8
        for (int k = 0; k < 64; ++k) a += z1[k] * W2[k * 32 + t];
        z2[t] = fmaxf(a, 0.f);
    }
    __syncthreads();
    __shared__ float z3[8];
    if (t < 8) {
        float a = b3[t];
#pragma unroll
        for (int k = 0; k < 32; ++k) a += z2[k] * W3[k * 8 + t];
        z3[t] = a;
    }
    __syncthreads();
    if (t == 0) {
        float mx = z3[0];
#pragma unroll
        for (int j = 1; j < 8; ++j) mx = fmaxf(mx, z3[j]);
        float se = 0.f;
#pragma unroll
        for (int j = 0; j < 8; ++j) se += expf(z3[j] - mx);
        float lse = mx + logf(se);
#pragma unroll
        for (int j = 0; j < 8; ++j) out[g * 8 + j] = z3[j] - lse;
    }
}

extern "C" void kernel_launch(void* const* d_in, const int* in_sizes, int n_in,
                              void* d_out, int out_size, void* d_ws, size_t ws_size,
                              hipStream_t stream) {
    const float* x     = (const float*)d_in[0];
    const int*   edge  = (const int*)d_in[1];
    const int*   row   = edge;
    const int*   col   = edge + N_EDGES;
    const int*   batch = (const int*)d_in[2];
    const float* W_sgc = (const float*)d_in[3];
    const float* b_sgc = (const float*)d_in[4];
    const float* w_att = (const float*)d_in[5];
    const float* b_att = (const float*)d_in[6];
    const float* W1    = (const float*)d_in[7];
    const float* b1    = (const float*)d_in[8];
    const float* W2    = (const float*)d_in[9];
    const float* b2    = (const float*)d_in[10];
    const float* W3    = (const float*)d_in[11];
    const float* b3    = (const float*)d_in[12];
    float* out = (float*)d_out;

    char* p = (char*)d_ws;
    auto alloc = [&](size_t bytes) {
        char* r = p;
        p += (bytes + 255) & ~(size_t)255;
        return r;
    };
    int*      gcursor = (int*)alloc((size_t)NBUCK * 4);
    int*      gbound  = (int*)alloc((size_t)(NGRAPH + 1) * 4);
    int*      start   = (int*)alloc((size_t)N_NODES * 4);
    int*      counts  = (int*)alloc((size_t)N_NODES * 4);
    float*    dinv    = (float*)alloc((size_t)N_NODES * 4);
    float*    vraw    = (float*)alloc((size_t)N_NODES * 4);
    ushort_t* h0b     = (ushort_t*)alloc((size_t)N_NODES * 64 * 2);          // bf16
    unsigned char* h0s = (unsigned char*)alloc((size_t)(N_NODES + 1) * 64);  // fp8
    ushort_t* hAs     = (ushort_t*)alloc((size_t)(N_NODES + 1) * 32 * 2);    // fp8
    ushort_t* hBs     = (ushort_t*)alloc((size_t)(N_NODES + 1) * 32 * 2);    // fp8
    ushort_t* hfin    = (ushort_t*)alloc((size_t)N_NODES * 64 * 2);          // bf16 final h
    unsigned* csr4    = (unsigned*)alloc(((size_t)NBUCK * WINCAP + 64) * 4); // fixed windows
    unsigned* slab    = (unsigned*)alloc((size_t)NBUCK * BUCKCAP * 4);

    hipMemsetAsync(gcursor, 0, (size_t)NBUCK * 4, stream);

    k_binstage_bounds<<<NBIN_BLOCKS + NBOUND_BLOCKS, 256, 0, stream>>>(
        row, col, gcursor, slab, batch, gbound);
    k_bucket_build<<<NBUCK, 256, 0, stream>>>(slab, gcursor, start, counts, dinv, csr4);
    k_h0<<<(N_NODES / 16 + 3) / 4, 256, 0, stream>>>(x, W_sgc, b_sgc, dinv, h0b, h0s);
    k_hop<<<N_NODES / 8, 256, 0, stream>>>((const ushort_t*)h0s, (const ushort_t*)h0s,
                                           dinv, start, counts, csr4, hAs);
    k_hop<<<N_NODES / 8, 256, 0, stream>>>(hAs, (const ushort_t*)h0s,
                                           dinv, start, counts, csr4, hBs);
    k_hop_final<<<N_NODES / 8, 256, 0, stream>>>(hBs, (const unsigned*)h0b,
                                                 dinv, start, counts, csr4,
                                                 w_att, b_att, (unsigned*)hfin, vraw);
    k_readout_mlp<<<NGRAPH, 256, 0, stream>>>(hfin, vraw, gbound,
                                              W1, b1, W2, b2, W3, b3, out);
}